// Round 1
// baseline (102.705 us; speedup 1.0000x reference)
//
#include <hip/hip_runtime.h>
#include <math.h>

// Problem constants (fixed by reference setup_inputs)
#define BSZ   16
#define NA    3
#define NH    80
#define NW    80
#define NC    80
#define HW    (NH * NW)                 // 6400
#define CELLS (BSZ * NA * NH * NW)      // 307200
#define EPSL  1e-07f
#define BLK   256
#define NBLK  (CELLS / BLK)             // 1200

__device__ __forceinline__ float bce_logits(float z, float t) {
    // max(z,0) - z*t + log1p(exp(-|z|))
    return fmaxf(z, 0.0f) - z * t + log1pf(expf(-fabsf(z)));
}

__global__ __launch_bounds__(BLK) void yolo_loss_main(
    const float* __restrict__ input,
    const float* __restrict__ mask,
    const float* __restrict__ obj_mask,
    const float* __restrict__ tx,
    const float* __restrict__ ty,
    const float* __restrict__ tw,
    const float* __restrict__ th,
    const float* __restrict__ tgt_scale,
    const float* __restrict__ tcls,
    float* __restrict__ ws)
{
    const int cell = blockIdx.x * BLK + threadIdx.x;

    float s_xy = 0.f, s_wh = 0.f, s_iou = 0.f, s_conf = 0.f, s_cls = 0.f;

    if (cell < CELLS) {
        const int w_i = cell % NW;
        const int h_i = (cell / NW) % NH;
        const int a_i = (cell / HW) % NA;
        const int b_i = cell / (NA * HW);

        // input[b, a*85 + c, h, w]; per fixed c, lanes (adjacent w) are coalesced
        const float* pbase = input
            + ((size_t)(b_i * NA + a_i) * (5 + NC)) * HW
            + (size_t)h_i * NW + w_i;

        const float zx = pbase[0 * HW];
        const float zy = pbase[1 * HW];
        const float pw = pbase[2 * HW];
        const float ph = pbase[3 * HW];
        const float zc = pbase[4 * HW];

        const float m  = mask[cell];
        const float om = obj_mask[cell];
        const float gx = tx[cell];
        const float gy = ty[cell];
        const float gw = tw[cell];
        const float gh = th[cell];
        const float ts = tgt_scale[cell];

        const float x = 1.0f / (1.0f + expf(-zx));
        const float y = 1.0f / (1.0f + expf(-zy));

        // loss_xy / loss_wh partial sums
        s_xy = ts * (fabsf(x - gx) + fabsf(y - gy));
        s_wh = ts * (fabsf(pw - gw) + fabsf(ph - gh));

        // conf BCE
        s_conf = om * bce_logits(zc, m);

        // CIOU (mirrors reference arithmetic in fp32)
        {
            const float p_x1 = x - pw * 0.5f, p_x2 = x + pw * 0.5f;
            const float p_y1 = y - ph * 0.5f, p_y2 = y + ph * 0.5f;
            const float g_x1 = gx - gw * 0.5f, g_x2 = gx + gw * 0.5f;
            const float g_y1 = gy - gh * 0.5f, g_y2 = gy + gh * 0.5f;

            const float iw = fmaxf(fminf(p_x2, g_x2) - fmaxf(p_x1, g_x1), 0.0f);
            const float ih = fmaxf(fminf(p_y2, g_y2) - fmaxf(p_y1, g_y1), 0.0f);
            const float inter = iw * ih;
            const float uni   = pw * ph + gw * gh - inter + EPSL;
            const float iou   = inter / uni;

            const float cw = fmaxf(p_x2, g_x2) - fminf(p_x1, g_x1);
            const float ch = fmaxf(p_y2, g_y2) - fminf(p_y1, g_y1);
            const float c2 = cw * cw + ch * ch + EPSL;
            const float rho2 = (x - gx) * (x - gx) + (y - gy) * (y - gy);

            const float da = atanf(gw / (gh + EPSL)) - atanf(pw / (ph + EPSL));
            const float v  = (4.0f / (float)(M_PI * M_PI)) * da * da;
            const float alpha = v / (v - iou + 1.0f + EPSL);

            const float lbox = 1.0f - (iou - (rho2 / c2 + v * alpha));
            s_iou = m * ts * lbox;
        }

        // class BCE: 80 channels. tcls is cell-contiguous -> float4 loads.
        {
            const float4* tc4 = (const float4*)(tcls + (size_t)cell * NC);
            float acc = 0.f;
            #pragma unroll 4
            for (int c4 = 0; c4 < NC / 4; ++c4) {
                const float4 t4 = tc4[c4];
                const float z0 = pbase[(size_t)(5 + 4 * c4 + 0) * HW];
                const float z1 = pbase[(size_t)(5 + 4 * c4 + 1) * HW];
                const float z2 = pbase[(size_t)(5 + 4 * c4 + 2) * HW];
                const float z3 = pbase[(size_t)(5 + 4 * c4 + 3) * HW];
                acc += bce_logits(z0, t4.x);
                acc += bce_logits(z1, t4.y);
                acc += bce_logits(z2, t4.z);
                acc += bce_logits(z3, t4.w);
            }
            s_cls = m * acc;
        }
    }

    // Block reduction: wave shuffle then LDS across the 4 waves.
    float vals[5] = { s_xy, s_wh, s_iou, s_conf, s_cls };
    #pragma unroll
    for (int j = 0; j < 5; ++j) {
        float v = vals[j];
        #pragma unroll
        for (int off = 32; off > 0; off >>= 1)
            v += __shfl_down(v, off, 64);
        vals[j] = v;
    }

    __shared__ float red[4][5];
    const int lane = threadIdx.x & 63;
    const int wid  = threadIdx.x >> 6;
    if (lane == 0) {
        #pragma unroll
        for (int j = 0; j < 5; ++j) red[wid][j] = vals[j];
    }
    __syncthreads();
    if (threadIdx.x == 0) {
        #pragma unroll
        for (int j = 0; j < 5; ++j)
            ws[(size_t)blockIdx.x * 5 + j] =
                red[0][j] + red[1][j] + red[2][j] + red[3][j];
    }
}

// Deterministic final reduction: one block, fixed summation order per thread,
// fixed shuffle tree -> identical result every replay.
__global__ __launch_bounds__(BLK) void yolo_loss_final(
    const float* __restrict__ ws, float* __restrict__ out)
{
    const float scale[5] = { 1.0f / (BSZ * BSZ), 1.0f / (BSZ * BSZ),
                             1.0f / BSZ, 1.0f / BSZ, 1.0f / BSZ };
    __shared__ float red[4];
    const int lane = threadIdx.x & 63;
    const int wid  = threadIdx.x >> 6;

    for (int j = 0; j < 5; ++j) {
        float v = 0.f;
        for (int i = threadIdx.x; i < NBLK; i += BLK)
            v += ws[(size_t)i * 5 + j];
        #pragma unroll
        for (int off = 32; off > 0; off >>= 1)
            v += __shfl_down(v, off, 64);
        if (lane == 0) red[wid] = v;
        __syncthreads();
        if (threadIdx.x == 0)
            out[j] = (red[0] + red[1] + red[2] + red[3]) * scale[j];
        __syncthreads();
    }
}

extern "C" void kernel_launch(void* const* d_in, const int* in_sizes, int n_in,
                              void* d_out, int out_size, void* d_ws, size_t ws_size,
                              hipStream_t stream) {
    const float* input     = (const float*)d_in[0];
    const float* mask      = (const float*)d_in[1];
    const float* obj_mask  = (const float*)d_in[2];
    const float* tx        = (const float*)d_in[3];
    const float* ty        = (const float*)d_in[4];
    const float* tw        = (const float*)d_in[5];
    const float* th        = (const float*)d_in[6];
    const float* tgt_scale = (const float*)d_in[7];
    const float* tcls      = (const float*)d_in[8];
    float* out = (float*)d_out;
    float* ws  = (float*)d_ws;   // needs NBLK*5*4 = 24000 bytes

    yolo_loss_main<<<NBLK, BLK, 0, stream>>>(
        input, mask, obj_mask, tx, ty, tw, th, tgt_scale, tcls, ws);
    yolo_loss_final<<<1, BLK, 0, stream>>>(ws, out);
}

// Round 2
// 82.619 us; speedup vs baseline: 1.2431x; 1.2431x over previous
//
#include <hip/hip_runtime.h>
#include <math.h>

// Problem constants (fixed by reference setup_inputs)
#define BSZ   16
#define NA    3
#define NH    80
#define NW    80
#define NC    80
#define HW    (NH * NW)                 // 6400
#define CELLS (BSZ * NA * NH * NW)      // 307200
#define EPSL  1e-07f
#define BLK   256
#define CPT   4                         // cells per thread (float4 along hw)
#define NTH   (CELLS / CPT)             // 76800
#define NBLK  (NTH / BLK)               // 300

#define L2E 1.4426950408889634f
#define LN2 0.6931471805599453f

__device__ __forceinline__ float fexp2(float x) { return __builtin_amdgcn_exp2f(x); }
__device__ __forceinline__ float flog2(float x) { return __builtin_amdgcn_logf(x); }
__device__ __forceinline__ float frcp(float x)  { return __builtin_amdgcn_rcpf(x); }

// max(z,0) - z*t + log1p(exp(-|z|)) via HW exp2/log2 (v_exp_f32 / v_log_f32)
__device__ __forceinline__ float bce_fast(float z, float t) {
    const float e  = fexp2(-fabsf(z) * L2E);
    const float sp = LN2 * flog2(1.0f + e);
    return fmaxf(z, 0.0f) - z * t + sp;
}

__device__ __forceinline__ float sigmoid_fast(float z) {
    return frcp(1.0f + fexp2(-z * L2E));
}

__global__ __launch_bounds__(BLK) void yolo_loss_main(
    const float* __restrict__ input,
    const float* __restrict__ mask,
    const float* __restrict__ obj_mask,
    const float* __restrict__ tx,
    const float* __restrict__ ty,
    const float* __restrict__ tw,
    const float* __restrict__ th,
    const float* __restrict__ tgt_scale,
    const float* __restrict__ tcls,
    float* __restrict__ ws)
{
    const int idx   = blockIdx.x * BLK + threadIdx.x;   // [0, NTH)
    const int hw4   = idx % (HW / CPT);                 // 0..1599
    const int plane = idx / (HW / CPT);                 // b*NA+a, 0..47
    const int hw    = hw4 * CPT;                        // aligned to 4

    // input[plane, c, hw..hw+3] — 16B aligned (HW % 4 == 0)
    const float* pbase = input + (size_t)plane * (5 + NC) * HW + hw;
    const int    cb    = plane * HW + hw;               // cell base for masks

    float zx[4], zy[4], pw[4], ph[4], zc[4];
    *(float4*)zx = *(const float4*)(pbase + 0 * HW);
    *(float4*)zy = *(const float4*)(pbase + 1 * HW);
    *(float4*)pw = *(const float4*)(pbase + 2 * HW);
    *(float4*)ph = *(const float4*)(pbase + 3 * HW);
    *(float4*)zc = *(const float4*)(pbase + 4 * HW);

    float m[4], om[4], gx[4], gy[4], gw[4], gh[4], ts[4];
    *(float4*)m  = *(const float4*)(mask      + cb);
    *(float4*)om = *(const float4*)(obj_mask  + cb);
    *(float4*)gx = *(const float4*)(tx        + cb);
    *(float4*)gy = *(const float4*)(ty        + cb);
    *(float4*)gw = *(const float4*)(tw        + cb);
    *(float4*)gh = *(const float4*)(th        + cb);
    *(float4*)ts = *(const float4*)(tgt_scale + cb);

    float s_xy = 0.f, s_wh = 0.f, s_iou = 0.f, s_conf = 0.f, s_cls = 0.f;

    #pragma unroll
    for (int k = 0; k < CPT; ++k) {
        const float x = sigmoid_fast(zx[k]);
        const float y = sigmoid_fast(zy[k]);

        s_xy  += ts[k] * (fabsf(x - gx[k]) + fabsf(y - gy[k]));
        s_wh  += ts[k] * (fabsf(pw[k] - gw[k]) + fabsf(ph[k] - gh[k]));
        s_conf += om[k] * bce_fast(zc[k], m[k]);

        // CIOU (reference arithmetic; divisions via v_rcp)
        const float p_x1 = x - pw[k] * 0.5f, p_x2 = x + pw[k] * 0.5f;
        const float p_y1 = y - ph[k] * 0.5f, p_y2 = y + ph[k] * 0.5f;
        const float g_x1 = gx[k] - gw[k] * 0.5f, g_x2 = gx[k] + gw[k] * 0.5f;
        const float g_y1 = gy[k] - gh[k] * 0.5f, g_y2 = gy[k] + gh[k] * 0.5f;

        const float iw = fmaxf(fminf(p_x2, g_x2) - fmaxf(p_x1, g_x1), 0.0f);
        const float ih = fmaxf(fminf(p_y2, g_y2) - fmaxf(p_y1, g_y1), 0.0f);
        const float inter = iw * ih;
        const float uni   = pw[k] * ph[k] + gw[k] * gh[k] - inter + EPSL;
        const float iou   = inter * frcp(uni);

        const float cw = fmaxf(p_x2, g_x2) - fminf(p_x1, g_x1);
        const float ch = fmaxf(p_y2, g_y2) - fminf(p_y1, g_y1);
        const float c2 = cw * cw + ch * ch + EPSL;
        const float rho2 = (x - gx[k]) * (x - gx[k]) + (y - gy[k]) * (y - gy[k]);

        const float da = atanf(gw[k] * frcp(gh[k] + EPSL))
                       - atanf(pw[k] * frcp(ph[k] + EPSL));
        const float v  = (4.0f / (float)(M_PI * M_PI)) * da * da;
        const float alpha = v * frcp(v - iou + 1.0f + EPSL);

        const float lbox = 1.0f - (iou - (rho2 * frcp(c2) + v * alpha));
        s_iou += m[k] * ts[k] * lbox;
    }

    // class BCE: 80 channels x 4 cells, all float4 loads
    {
        const float* tcb = tcls + (size_t)cb * NC;   // 4 cells x 80 contiguous
        float accc[4] = {0.f, 0.f, 0.f, 0.f};
        #pragma unroll 2
        for (int c4 = 0; c4 < NC / 4; ++c4) {
            float zj[4][4];  // [channel j in group][cell k]
            #pragma unroll
            for (int j = 0; j < 4; ++j)
                *(float4*)zj[j] = *(const float4*)(pbase + (size_t)(5 + 4 * c4 + j) * HW);
            float tk[4][4];  // [cell k][channel j in group]
            #pragma unroll
            for (int k = 0; k < 4; ++k)
                *(float4*)tk[k] = *(const float4*)(tcb + k * NC + 4 * c4);
            #pragma unroll
            for (int j = 0; j < 4; ++j)
                #pragma unroll
                for (int k = 0; k < 4; ++k)
                    accc[k] += bce_fast(zj[j][k], tk[k][j]);
        }
        s_cls = m[0] * accc[0] + m[1] * accc[1] + m[2] * accc[2] + m[3] * accc[3];
    }

    // Block reduction: wave shuffle then LDS across the 4 waves.
    float vals[5] = { s_xy, s_wh, s_iou, s_conf, s_cls };
    #pragma unroll
    for (int j = 0; j < 5; ++j) {
        float v = vals[j];
        #pragma unroll
        for (int off = 32; off > 0; off >>= 1)
            v += __shfl_down(v, off, 64);
        vals[j] = v;
    }

    __shared__ float red[4][5];
    const int lane = threadIdx.x & 63;
    const int wid  = threadIdx.x >> 6;
    if (lane == 0) {
        #pragma unroll
        for (int j = 0; j < 5; ++j) red[wid][j] = vals[j];
    }
    __syncthreads();
    if (threadIdx.x == 0) {
        #pragma unroll
        for (int j = 0; j < 5; ++j)
            ws[(size_t)blockIdx.x * 5 + j] =
                red[0][j] + red[1][j] + red[2][j] + red[3][j];
    }
}

// Deterministic final reduction: one block, fixed order -> identical every replay.
__global__ __launch_bounds__(BLK) void yolo_loss_final(
    const float* __restrict__ ws, float* __restrict__ out)
{
    const float scale[5] = { 1.0f / (BSZ * BSZ), 1.0f / (BSZ * BSZ),
                             1.0f / BSZ, 1.0f / BSZ, 1.0f / BSZ };
    __shared__ float red[4];
    const int lane = threadIdx.x & 63;
    const int wid  = threadIdx.x >> 6;

    for (int j = 0; j < 5; ++j) {
        float v = 0.f;
        for (int i = threadIdx.x; i < NBLK; i += BLK)
            v += ws[(size_t)i * 5 + j];
        #pragma unroll
        for (int off = 32; off > 0; off >>= 1)
            v += __shfl_down(v, off, 64);
        if (lane == 0) red[wid] = v;
        __syncthreads();
        if (threadIdx.x == 0)
            out[j] = (red[0] + red[1] + red[2] + red[3]) * scale[j];
        __syncthreads();
    }
}

extern "C" void kernel_launch(void* const* d_in, const int* in_sizes, int n_in,
                              void* d_out, int out_size, void* d_ws, size_t ws_size,
                              hipStream_t stream) {
    const float* input     = (const float*)d_in[0];
    const float* mask      = (const float*)d_in[1];
    const float* obj_mask  = (const float*)d_in[2];
    const float* tx        = (const float*)d_in[3];
    const float* ty        = (const float*)d_in[4];
    const float* tw        = (const float*)d_in[5];
    const float* th        = (const float*)d_in[6];
    const float* tgt_scale = (const float*)d_in[7];
    const float* tcls      = (const float*)d_in[8];
    float* out = (float*)d_out;
    float* ws  = (float*)d_ws;   // needs NBLK*5*4 = 6000 bytes

    yolo_loss_main<<<NBLK, BLK, 0, stream>>>(
        input, mask, obj_mask, tx, ty, tw, th, tgt_scale, tcls, ws);
    yolo_loss_final<<<1, BLK, 0, stream>>>(ws, out);
}

// Round 3
// 64.945 us; speedup vs baseline: 1.5814x; 1.2721x over previous
//
#include <hip/hip_runtime.h>
#include <math.h>

// Problem constants (fixed by reference setup_inputs)
#define BSZ   16
#define NA    3
#define NH    80
#define NW    80
#define NC    80
#define HW    (NH * NW)                 // 6400
#define CELLS (BSZ * NA * NH * NW)      // 307200
#define EPSL  1e-07f
#define BLK   256
#define CPT   4                         // cells per thread (float4 along hw)
#define NSEG  (CELLS / CPT / BLK)       // 300 cell-segments
#define NSPLIT 4                        // class-chunks of 20 channels
#define NBLK  (NSEG * NSPLIT)           // 1200 blocks
#define CCH   (NC / NSPLIT)             // 20 channels per chunk

#define L2E 1.4426950408889634f
#define LN2 0.6931471805599453f

__device__ __forceinline__ float fexp2(float x) { return __builtin_amdgcn_exp2f(x); }
__device__ __forceinline__ float flog2(float x) { return __builtin_amdgcn_logf(x); }
__device__ __forceinline__ float frcp(float x)  { return __builtin_amdgcn_rcpf(x); }

// max(z,0) - z*t + log1p(exp(-|z|)) via HW exp2/log2
__device__ __forceinline__ float bce_fast(float z, float t) {
    const float e  = fexp2(-fabsf(z) * L2E);
    const float sp = LN2 * flog2(1.0f + e);
    return fmaxf(z, 0.0f) - z * t + sp;
}

__device__ __forceinline__ float sigmoid_fast(float z) {
    return frcp(1.0f + fexp2(-z * L2E));
}

__global__ __launch_bounds__(BLK) void yolo_loss_main(
    const float* __restrict__ input,
    const float* __restrict__ mask,
    const float* __restrict__ obj_mask,
    const float* __restrict__ tx,
    const float* __restrict__ ty,
    const float* __restrict__ tw,
    const float* __restrict__ th,
    const float* __restrict__ tgt_scale,
    const float* __restrict__ tcls,
    float* __restrict__ ws)
{
    const int cc  = blockIdx.x & (NSPLIT - 1);  // class-chunk id (uniform per block)
    const int seg = blockIdx.x / NSPLIT;        // cell segment
    const int t   = seg * BLK + threadIdx.x;    // [0, CELLS/CPT)
    const int hw4   = t % (HW / CPT);
    const int plane = t / (HW / CPT);           // b*NA+a, 0..47
    const int hw    = hw4 * CPT;

    const float* pbase = input + (size_t)plane * (5 + NC) * HW + hw;
    const int    cb    = plane * HW + hw;

    float m[4];
    *(float4*)m = *(const float4*)(mask + cb);

    float s_xy = 0.f, s_wh = 0.f, s_iou = 0.f, s_conf = 0.f, s_cls = 0.f;

    // ---- class BCE for this 20-channel chunk, 4 cells ----
    {
        const int c0 = cc * CCH;
        const float* zb  = pbase + (size_t)(5 + c0) * HW;
        const float* tcb = tcls + (size_t)cb * NC + c0;
        float accc[4] = {0.f, 0.f, 0.f, 0.f};
        #pragma unroll
        for (int c4 = 0; c4 < CCH / 4; ++c4) {          // 5 groups of 4 channels
            float zj[4][4];  // [channel j][cell k]
            #pragma unroll
            for (int j = 0; j < 4; ++j)
                *(float4*)zj[j] = *(const float4*)(zb + (size_t)(4 * c4 + j) * HW);
            float tk[4][4];  // [cell k][channel j]
            #pragma unroll
            for (int k = 0; k < 4; ++k)
                *(float4*)tk[k] = *(const float4*)(tcb + k * NC + 4 * c4);
            #pragma unroll
            for (int j = 0; j < 4; ++j)
                #pragma unroll
                for (int k = 0; k < 4; ++k)
                    accc[k] += bce_fast(zj[j][k], tk[k][j]);
        }
        s_cls = m[0] * accc[0] + m[1] * accc[1] + m[2] * accc[2] + m[3] * accc[3];
    }

    // ---- box / conf / CIOU: only chunk-0 blocks (whole block uniform) ----
    if (cc == 0) {
        float zx[4], zy[4], pw[4], ph[4], zc[4];
        *(float4*)zx = *(const float4*)(pbase + 0 * HW);
        *(float4*)zy = *(const float4*)(pbase + 1 * HW);
        *(float4*)pw = *(const float4*)(pbase + 2 * HW);
        *(float4*)ph = *(const float4*)(pbase + 3 * HW);
        *(float4*)zc = *(const float4*)(pbase + 4 * HW);

        float om[4], gx[4], gy[4], gw[4], gh[4], ts[4];
        *(float4*)om = *(const float4*)(obj_mask  + cb);
        *(float4*)gx = *(const float4*)(tx        + cb);
        *(float4*)gy = *(const float4*)(ty        + cb);
        *(float4*)gw = *(const float4*)(tw        + cb);
        *(float4*)gh = *(const float4*)(th        + cb);
        *(float4*)ts = *(const float4*)(tgt_scale + cb);

        #pragma unroll
        for (int k = 0; k < CPT; ++k) {
            const float x = sigmoid_fast(zx[k]);
            const float y = sigmoid_fast(zy[k]);

            s_xy  += ts[k] * (fabsf(x - gx[k]) + fabsf(y - gy[k]));
            s_wh  += ts[k] * (fabsf(pw[k] - gw[k]) + fabsf(ph[k] - gh[k]));
            s_conf += om[k] * bce_fast(zc[k], m[k]);

            const float p_x1 = x - pw[k] * 0.5f, p_x2 = x + pw[k] * 0.5f;
            const float p_y1 = y - ph[k] * 0.5f, p_y2 = y + ph[k] * 0.5f;
            const float g_x1 = gx[k] - gw[k] * 0.5f, g_x2 = gx[k] + gw[k] * 0.5f;
            const float g_y1 = gy[k] - gh[k] * 0.5f, g_y2 = gy[k] + gh[k] * 0.5f;

            const float iw = fmaxf(fminf(p_x2, g_x2) - fmaxf(p_x1, g_x1), 0.0f);
            const float ih = fmaxf(fminf(p_y2, g_y2) - fmaxf(p_y1, g_y1), 0.0f);
            const float inter = iw * ih;
            const float uni   = pw[k] * ph[k] + gw[k] * gh[k] - inter + EPSL;
            const float iou   = inter * frcp(uni);

            const float cw = fmaxf(p_x2, g_x2) - fminf(p_x1, g_x1);
            const float ch = fmaxf(p_y2, g_y2) - fminf(p_y1, g_y1);
            const float c2 = cw * cw + ch * ch + EPSL;
            const float rho2 = (x - gx[k]) * (x - gx[k]) + (y - gy[k]) * (y - gy[k]);

            const float da = atanf(gw[k] * frcp(gh[k] + EPSL))
                           - atanf(pw[k] * frcp(ph[k] + EPSL));
            const float v  = (4.0f / (float)(M_PI * M_PI)) * da * da;
            const float alpha = v * frcp(v - iou + 1.0f + EPSL);

            const float lbox = 1.0f - (iou - (rho2 * frcp(c2) + v * alpha));
            s_iou += m[k] * ts[k] * lbox;
        }
    }

    // Block reduction: wave shuffle then LDS across the 4 waves.
    float vals[5] = { s_xy, s_wh, s_iou, s_conf, s_cls };
    #pragma unroll
    for (int j = 0; j < 5; ++j) {
        float v = vals[j];
        #pragma unroll
        for (int off = 32; off > 0; off >>= 1)
            v += __shfl_down(v, off, 64);
        vals[j] = v;
    }

    __shared__ float red[4][5];
    const int lane = threadIdx.x & 63;
    const int wid  = threadIdx.x >> 6;
    if (lane == 0) {
        #pragma unroll
        for (int j = 0; j < 5; ++j) red[wid][j] = vals[j];
    }
    __syncthreads();
    if (threadIdx.x == 0) {
        #pragma unroll
        for (int j = 0; j < 5; ++j)
            ws[(size_t)blockIdx.x * 5 + j] =
                red[0][j] + red[1][j] + red[2][j] + red[3][j];
    }
}

// Deterministic final reduction: one block, fixed order -> identical every replay.
__global__ __launch_bounds__(BLK) void yolo_loss_final(
    const float* __restrict__ ws, float* __restrict__ out)
{
    const float scale[5] = { 1.0f / (BSZ * BSZ), 1.0f / (BSZ * BSZ),
                             1.0f / BSZ, 1.0f / BSZ, 1.0f / BSZ };
    __shared__ float red[4];
    const int lane = threadIdx.x & 63;
    const int wid  = threadIdx.x >> 6;

    for (int j = 0; j < 5; ++j) {
        float v = 0.f;
        for (int i = threadIdx.x; i < NBLK; i += BLK)
            v += ws[(size_t)i * 5 + j];
        #pragma unroll
        for (int off = 32; off > 0; off >>= 1)
            v += __shfl_down(v, off, 64);
        if (lane == 0) red[wid] = v;
        __syncthreads();
        if (threadIdx.x == 0)
            out[j] = (red[0] + red[1] + red[2] + red[3]) * scale[j];
        __syncthreads();
    }
}

extern "C" void kernel_launch(void* const* d_in, const int* in_sizes, int n_in,
                              void* d_out, int out_size, void* d_ws, size_t ws_size,
                              hipStream_t stream) {
    const float* input     = (const float*)d_in[0];
    const float* mask      = (const float*)d_in[1];
    const float* obj_mask  = (const float*)d_in[2];
    const float* tx        = (const float*)d_in[3];
    const float* ty        = (const float*)d_in[4];
    const float* tw        = (const float*)d_in[5];
    const float* th        = (const float*)d_in[6];
    const float* tgt_scale = (const float*)d_in[7];
    const float* tcls      = (const float*)d_in[8];
    float* out = (float*)d_out;
    float* ws  = (float*)d_ws;   // needs NBLK*5*4 = 24000 bytes

    yolo_loss_main<<<NBLK, BLK, 0, stream>>>(
        input, mask, obj_mask, tx, ty, tw, th, tgt_scale, tcls, ws);
    yolo_loss_final<<<1, BLK, 0, stream>>>(ws, out);
}